// Round 12
// baseline (704.006 us; speedup 1.0000x reference)
//
#include <hip/hip_runtime.h>
#include <hip/hip_bf16.h>
#include <hip/hip_fp16.h>
#include <cstdint>
#include <cstddef>

#define NNODES 50000
#define NEDGES 800000
#define DF 64
#define SROW 264    // LDS row stride in bf16 (528 B, 16B-aligned; proven r3/r6/r11)
#define NT 6250     // 800000/128 edge tiles
#define GST 512     // persistent blocks (2/CU)

typedef __bf16 bf16_t;
typedef __bf16 bf16x8 __attribute__((ext_vector_type(8)));
typedef __bf16 bf16x4 __attribute__((ext_vector_type(4)));
typedef float  f32x4  __attribute__((ext_vector_type(4)));
typedef _Float16 f16x2 __attribute__((ext_vector_type(2)));

// lgkm-only barrier: syncs LDS producer/consumer across waves WITHOUT draining
// vmcnt — staged global loads stay in flight across it (T4-lite). All cross-wave
// hazards in these kernels are LDS-only. "memory" clobber orders the ds ops.
__device__ __forceinline__ void bar_lds() {
    asm volatile("s_waitcnt lgkmcnt(0)\n\ts_barrier" ::: "memory");
}

// ---------------------------------------------------------------------------
// Weight packing: W[K][N] fp32 row-major -> bf16 MFMA B-fragments.
// Fragment (kblk, ct): lane l, elem j holds W[kblk*32 + (l>>4)*8 + j][ct*16 + (l&15)]
// Flat: ((kblk*(N/16) + ct)*64 + l)*8 + j.
// Segments: Wm1 @0 (49152), Wm2 @49152 (16384), Wu1 @65536 (32768), Wu2 @98304 (16384).
// ---------------------------------------------------------------------------
__global__ void prep_kernel(const float* __restrict__ Wm1, const float* __restrict__ Wm2,
                            const float* __restrict__ Wu1, const float* __restrict__ Wu2,
                            bf16_t* __restrict__ wp)
{
    int idx = blockIdx.x * 256 + threadIdx.x;
    const float* src; int N; int off; int local;
    if (idx < 49152)       { src = Wm1; N = 256; off = 0;     local = idx; }
    else if (idx < 65536)  { src = Wm2; N = 64;  off = 49152; local = idx - 49152; }
    else if (idx < 98304)  { src = Wu1; N = 256; off = 65536; local = idx - 65536; }
    else if (idx < 114688) { src = Wu2; N = 64;  off = 98304; local = idx - 98304; }
    else return;
    int j    = local & 7;
    int l    = (local >> 3) & 63;
    int frag = local >> 9;
    int nct  = N >> 4;
    int kblk = frag / nct;
    int ct   = frag - kblk * nct;
    int k = kblk * 32 + (l >> 4) * 8 + j;
    int n = ct * 16 + (l & 15);
    wp[off + local] = (bf16_t)src[(size_t)k * N + n];
}

__device__ __forceinline__ void st_bf16x4(bf16_t* p, float4 v) {
    bf16x4 bv;
    bv[0] = (bf16_t)v.x; bv[1] = (bf16_t)v.y; bv[2] = (bf16_t)v.z; bv[3] = (bf16_t)v.w;
    *reinterpret_cast<bf16x4*>(p) = bv;
}

// ---------------------------------------------------------------------------
// Message kernel: persistent-ish. 256 threads (4 FAT waves), 128-edge tiles,
// ~12 tiles/block, software-pipelined:
//   step1: issue tile(i+1) h_s/h_r gathers -> regs (idx from LDS dbuf)
//          + issue tile(i+2) idx loads -> regs
//   step2: layer1 MFMA  (wave w: all 128 edges x cols [w*64,+64), acc[4][8]=128)
//   step3: c1 -> LDS (bias+relu)
//   step4: issue tile(i+1) e loads -> regs; layer2 MFMA (wave w: 128 x 16 cols);
//          pk-f16 atomic scatter
//   step5: staged regs -> LDS (tile i+1 input), idx(i+2) -> LDS
// All barriers lgkm-only: staged vmcnt loads stay in flight across them.
// launch_bounds(256,2): 256-reg budget. Peak ~230 regs (acc128+staged64+misc).
// ---------------------------------------------------------------------------
template<bool H2>
__global__ __launch_bounds__(256, 2)
void msg_kernel(const float* __restrict__ h, const float* __restrict__ efeat,
                const int* __restrict__ snd, const int* __restrict__ rcv,
                const bf16_t* __restrict__ Wp1, const float* __restrict__ b1,
                const bf16_t* __restrict__ Wp2, const float* __restrict__ b2,
                void* __restrict__ aggv)
{
    __shared__ bf16_t s_buf[128 * SROW];     // 67584 B
    __shared__ int s_idx[2][2][128];         // [parity][snd/rcv][row], 2 KB

    const int t = threadIdx.x;
    const int w = t >> 6;
    const int l = t & 63;
    const int q = l >> 4;
    const int r = l & 15;

    int tile = blockIdx.x;

    // loop-invariant per-thread constants
    float bias1v[4];
    #pragma unroll
    for (int g = 0; g < 4; ++g) bias1v[g] = b1[(w * 4 + g) * 16 + r];
    const int  cp  = w * 16 + (r & ~1);      // scatter col pair (H2)
    const bool odd = (r & 1);
    const float blo = b2[cp], bhi = b2[cp + 1];
    const float bias2s = b2[w * 16 + r];     // fallback scatter bias

    // ---- prologue: idx(k=0), idx(k=1), gather tile0 ----
    if (t < 128) {
        s_idx[0][0][t] = snd[(size_t)tile * 128 + t];
        s_idx[0][1][t] = rcv[(size_t)tile * 128 + t];
        if (tile + GST < NT) {
            s_idx[1][0][t] = snd[(size_t)(tile + GST) * 128 + t];
            s_idx[1][1][t] = rcv[(size_t)(tile + GST) * 128 + t];
        }
    }
    bar_lds();
    {
        const size_t e0 = (size_t)tile * 128;
        #pragma unroll
        for (int it = 0; it < 8; ++it) {
            int i = t + it * 256; int row = i >> 4; int c4 = (i & 15) * 4;
            float4 v = *reinterpret_cast<const float4*>(efeat + (e0 + row) * DF + c4);
            st_bf16x4(&s_buf[row * SROW + c4], v);
        }
        #pragma unroll
        for (int it = 0; it < 8; ++it) {
            int i = t + it * 256; int row = i >> 4; int c4 = (i & 15) * 4;
            float4 v = *reinterpret_cast<const float4*>(h + (size_t)s_idx[0][0][row] * DF + c4);
            st_bf16x4(&s_buf[row * SROW + DF + c4], v);
        }
        #pragma unroll
        for (int it = 0; it < 8; ++it) {
            int i = t + it * 256; int row = i >> 4; int c4 = (i & 15) * 4;
            float4 v = *reinterpret_cast<const float4*>(h + (size_t)s_idx[0][1][row] * DF + c4);
            st_bf16x4(&s_buf[row * SROW + 2 * DF + c4], v);
        }
    }
    bar_lds();

    for (int k = 0; tile < NT; tile += GST, ++k) {
        const bool hn  = (tile + GST < NT);
        const bool hn2 = (tile + 2 * GST < NT);
        const int  pc  = k & 1;
        const int  pn  = pc ^ 1;

        // ---- step 1: stage next tile's h-gathers (latency hides under L1) ----
        float4 hs[8], hr[8];
        if (hn) {
            #pragma unroll
            for (int it = 0; it < 8; ++it) {
                int i = t + it * 256; int row = i >> 4; int c4 = (i & 15) * 4;
                hs[it] = *reinterpret_cast<const float4*>(h + (size_t)s_idx[pn][0][row] * DF + c4);
            }
            #pragma unroll
            for (int it = 0; it < 8; ++it) {
                int i = t + it * 256; int row = i >> 4; int c4 = (i & 15) * 4;
                hr[it] = *reinterpret_cast<const float4*>(h + (size_t)s_idx[pn][1][row] * DF + c4);
            }
        }
        int nsnd = 0, nrcv = 0;
        if (hn2 && t < 128) {
            nsnd = snd[(size_t)(tile + 2 * GST) * 128 + t];
            nrcv = rcv[(size_t)(tile + 2 * GST) * 128 + t];
        }

        // ---- step 2: layer1 (wave w: 128 edges x 64 cols) ----
        f32x4 acc[4][8];
        #pragma unroll
        for (int g = 0; g < 4; ++g)
            #pragma unroll
            for (int am = 0; am < 8; ++am) acc[g][am] = (f32x4){0.f, 0.f, 0.f, 0.f};

        #pragma unroll
        for (int kb = 0; kb < 6; ++kb) {
            bf16x8 bfr[4];
            #pragma unroll
            for (int g = 0; g < 4; ++g)
                bfr[g] = *reinterpret_cast<const bf16x8*>(Wp1 + ((size_t)(kb * 16 + w * 4 + g) * 64 + l) * 8);
            #pragma unroll
            for (int am = 0; am < 8; ++am) {
                bf16x8 a = *reinterpret_cast<const bf16x8*>(&s_buf[(am * 16 + r) * SROW + kb * 32 + q * 8]);
                #pragma unroll
                for (int g = 0; g < 4; ++g)
                    acc[g][am] = __builtin_amdgcn_mfma_f32_16x16x32_bf16(a, bfr[g], acc[g][am], 0, 0, 0);
            }
        }
        bar_lds();

        // ---- step 3: c1 writeback (bias+relu) ----
        #pragma unroll
        for (int g = 0; g < 4; ++g) {
            const int col1 = (w * 4 + g) * 16 + r;
            #pragma unroll
            for (int am = 0; am < 8; ++am)
                #pragma unroll
                for (int j = 0; j < 4; ++j)
                    s_buf[(am * 16 + q * 4 + j) * SROW + col1] =
                        (bf16_t)fmaxf(acc[g][am][j] + bias1v[g], 0.f);
        }
        bar_lds();

        // ---- step 4: stage next e; layer2 (wave w: 128 edges x 16 cols); scatter ----
        float4 ev[8];
        if (hn) {
            const size_t e0n = (size_t)(tile + GST) * 128;
            #pragma unroll
            for (int it = 0; it < 8; ++it) {
                int i = t + it * 256; int row = i >> 4; int c4 = (i & 15) * 4;
                ev[it] = *reinterpret_cast<const float4*>(efeat + (e0n + row) * DF + c4);
            }
        }

        f32x4 acc2[8];
        #pragma unroll
        for (int am = 0; am < 8; ++am) acc2[am] = (f32x4){0.f, 0.f, 0.f, 0.f};

        #pragma unroll
        for (int kb = 0; kb < 8; ++kb) {
            bf16x8 b = *reinterpret_cast<const bf16x8*>(Wp2 + ((size_t)(kb * 4 + w) * 64 + l) * 8);
            #pragma unroll
            for (int am = 0; am < 8; ++am) {
                bf16x8 a = *reinterpret_cast<const bf16x8*>(&s_buf[(am * 16 + r) * SROW + kb * 32 + q * 8]);
                acc2[am] = __builtin_amdgcn_mfma_f32_16x16x32_bf16(a, b, acc2[am], 0, 0, 0);
            }
        }

        if constexpr (H2) {
            _Float16* aggh = (_Float16*)aggv;
            #pragma unroll
            for (int am = 0; am < 8; ++am) {
                float v0 = acc2[am][0], v1 = acc2[am][1], v2 = acc2[am][2], v3 = acc2[am][3];
                float p0 = __shfl_xor(v0, 1), p1 = __shfl_xor(v1, 1);
                float p2 = __shfl_xor(v2, 1), p3 = __shfl_xor(v3, 1);
                float loA = odd ? p2 : v0, hiA = odd ? v2 : p0;
                float loB = odd ? p3 : v1, hiB = odd ? v3 : p1;
                int jbase = odd ? 2 : 0;
                int erowA = am * 16 + q * 4 + jbase;
                f16x2 hA = { (_Float16)(loA + blo), (_Float16)(hiA + bhi) };
                f16x2 hB = { (_Float16)(loB + blo), (_Float16)(hiB + bhi) };
                __builtin_amdgcn_global_atomic_fadd_v2f16(
                    (f16x2*)(aggh + (size_t)s_idx[pc][1][erowA]     * DF + cp), hA);
                __builtin_amdgcn_global_atomic_fadd_v2f16(
                    (f16x2*)(aggh + (size_t)s_idx[pc][1][erowA + 1] * DF + cp), hB);
            }
        } else {
            float* agg = (float*)aggv;
            #pragma unroll
            for (int am = 0; am < 8; ++am)
                #pragma unroll
                for (int j = 0; j < 4; ++j) {
                    int erow = am * 16 + q * 4 + j;
                    atomicAdd(agg + (size_t)s_idx[pc][1][erow] * DF + w * 16 + r,
                              acc2[am][j] + bias2s);
                }
        }
        bar_lds();   // all c1 + idx reads of this tile done

        // ---- step 5: staged regs -> LDS (next tile), idx(i+2) -> LDS ----
        if (hn) {
            #pragma unroll
            for (int it = 0; it < 8; ++it) {
                int i = t + it * 256; int row = i >> 4; int c4 = (i & 15) * 4;
                st_bf16x4(&s_buf[row * SROW + c4], ev[it]);
            }
            #pragma unroll
            for (int it = 0; it < 8; ++it) {
                int i = t + it * 256; int row = i >> 4; int c4 = (i & 15) * 4;
                st_bf16x4(&s_buf[row * SROW + DF + c4], hs[it]);
            }
            #pragma unroll
            for (int it = 0; it < 8; ++it) {
                int i = t + it * 256; int row = i >> 4; int c4 = (i & 15) * 4;
                st_bf16x4(&s_buf[row * SROW + 2 * DF + c4], hr[it]);
            }
        }
        if (hn2 && t < 128) {
            s_idx[pc][0][t] = nsnd;
            s_idx[pc][1][t] = nrcv;
        }
        bar_lds();
    }
}

// ---------------------------------------------------------------------------
// Node-update kernel: r11's proven body; gather reads agg as f16 (H2) or
// f32 (fallback, alias-safe when agg==out: reads precede all stores).
// ---------------------------------------------------------------------------
template<bool H2>
__global__ __launch_bounds__(256, 4)
void upd_kernel(const float* __restrict__ h, const void* __restrict__ aggv,
                const bf16_t* __restrict__ Wp1, const float* __restrict__ b1,
                const bf16_t* __restrict__ Wp2, const float* __restrict__ b2,
                float* __restrict__ out)
{
    __shared__ bf16_t s_buf[64 * SROW];

    const int t  = threadIdx.x;
    const int n0 = blockIdx.x * 64;

    if constexpr (H2) {
        const _Float16* aggh = (const _Float16*)aggv;
        #pragma unroll
        for (int it = 0; it < 4; ++it) {
            int i = t + it * 256; int nn = i >> 4; int col = (i & 15) * 4;
            int node = n0 + nn;
            float4 v = {0.f, 0.f, 0.f, 0.f};
            if (node < NNODES) v = *reinterpret_cast<const float4*>(h + (size_t)node * DF + col);
            st_bf16x4(&s_buf[nn * SROW + col], v);
        }
        #pragma unroll
        for (int it = 0; it < 4; ++it) {
            int i = t + it * 256; int nn = i >> 4; int col = (i & 15) * 4;
            int node = n0 + nn;
            float4 v = {0.f, 0.f, 0.f, 0.f};
            if (node < NNODES) {
                f16x2 h01 = *reinterpret_cast<const f16x2*>(aggh + (size_t)node * DF + col);
                f16x2 h23 = *reinterpret_cast<const f16x2*>(aggh + (size_t)node * DF + col + 2);
                v.x = (float)h01[0]; v.y = (float)h01[1];
                v.z = (float)h23[0]; v.w = (float)h23[1];
            }
            st_bf16x4(&s_buf[nn * SROW + DF + col], v);
        }
    } else {
        const float* agg = (const float*)aggv;
        #pragma unroll
        for (int it = 0; it < 8; ++it) {
            int i = t + it * 256; int nn = i >> 5; int col = (i & 31) * 4;
            int node = n0 + nn;
            float4 v = {0.f, 0.f, 0.f, 0.f};
            if (node < NNODES) {
                const float* srcp = (col < DF) ? (h + (size_t)node * DF + col)
                                               : (agg + (size_t)node * DF + (col - DF));
                v = *reinterpret_cast<const float4*>(srcp);
            }
            st_bf16x4(&s_buf[nn * SROW + col], v);
        }
    }
    __syncthreads();

    const int w = t >> 6;
    const int l = t & 63;
    const int q = l >> 4;
    const int r = l & 15;

    f32x4 acc[4][4];
    #pragma unroll
    for (int g = 0; g < 4; ++g)
        #pragma unroll
        for (int am = 0; am < 4; ++am) acc[g][am] = (f32x4){0.f, 0.f, 0.f, 0.f};

    #pragma unroll
    for (int kb = 0; kb < 4; ++kb) {
        bf16x8 a[4];
        #pragma unroll
        for (int am = 0; am < 4; ++am)
            a[am] = *reinterpret_cast<const bf16x8*>(&s_buf[(am * 16 + r) * SROW + kb * 32 + q * 8]);
        #pragma unroll
        for (int g = 0; g < 4; ++g) {
            int ct = w * 4 + g;
            bf16x8 b = *reinterpret_cast<const bf16x8*>(Wp1 + ((size_t)(kb * 16 + ct) * 64 + l) * 8);
            #pragma unroll
            for (int am = 0; am < 4; ++am)
                acc[g][am] = __builtin_amdgcn_mfma_f32_16x16x32_bf16(a[am], b, acc[g][am], 0, 0, 0);
        }
    }
    __syncthreads();

    #pragma unroll
    for (int g = 0; g < 4; ++g) {
        int col = (w * 4 + g) * 16 + r;
        float bias = b1[col];
        #pragma unroll
        for (int am = 0; am < 4; ++am)
            #pragma unroll
            for (int j = 0; j < 4; ++j)
                s_buf[(am * 16 + q * 4 + j) * SROW + col] =
                    (bf16_t)fmaxf(acc[g][am][j] + bias, 0.f);
    }
    __syncthreads();

    f32x4 acc2[4];
    #pragma unroll
    for (int am = 0; am < 4; ++am) acc2[am] = (f32x4){0.f, 0.f, 0.f, 0.f};

    #pragma unroll
    for (int kb = 0; kb < 8; ++kb) {
        bf16x8 a[4];
        #pragma unroll
        for (int am = 0; am < 4; ++am)
            a[am] = *reinterpret_cast<const bf16x8*>(&s_buf[(am * 16 + r) * SROW + kb * 32 + q * 8]);
        bf16x8 b = *reinterpret_cast<const bf16x8*>(Wp2 + ((size_t)(kb * 4 + w) * 64 + l) * 8);
        #pragma unroll
        for (int am = 0; am < 4; ++am)
            acc2[am] = __builtin_amdgcn_mfma_f32_16x16x32_bf16(a[am], b, acc2[am], 0, 0, 0);
    }

    float bias2 = b2[w * 16 + r];
    #pragma unroll
    for (int am = 0; am < 4; ++am)
        #pragma unroll
        for (int j = 0; j < 4; ++j) {
            int node = n0 + am * 16 + q * 4 + j;
            if (node < NNODES) {
                int col = w * 16 + r;
                out[(size_t)node * DF + col] =
                    h[(size_t)node * DF + col] + acc2[am][j] + bias2;
            }
        }
}

extern "C" void kernel_launch(void* const* d_in, const int* in_sizes, int n_in,
                              void* d_out, int out_size, void* d_ws, size_t ws_size,
                              hipStream_t stream)
{
    const float* h    = (const float*)d_in[0];
    const float* e    = (const float*)d_in[1];
    const int*   snd  = (const int*)d_in[2];
    const int*   rcv  = (const int*)d_in[3];
    const float* W_m1 = (const float*)d_in[4];
    const float* b_m1 = (const float*)d_in[5];
    const float* W_m2 = (const float*)d_in[6];
    const float* b_m2 = (const float*)d_in[7];
    const float* W_u1 = (const float*)d_in[8];
    const float* b_u1 = (const float*)d_in[9];
    const float* W_u2 = (const float*)d_in[10];
    const float* b_u2 = (const float*)d_in[11];
    float* out = (float*)d_out;

    const size_t aggh_bytes = (size_t)NNODES * DF * sizeof(_Float16);  // 6.4 MB
    const size_t wp_bytes   = 114688 * sizeof(bf16_t);                 // 229 KB

    const bool useH2 = (ws_size >= aggh_bytes + wp_bytes);

    void*   aggv;
    bf16_t* wp;
    size_t  agg_clear;
    if (useH2) {
        aggv = d_ws;
        wp   = (bf16_t*)((char*)d_ws + aggh_bytes);
        agg_clear = aggh_bytes;
    } else {
        aggv = out;                       // legacy alias-safe f32 path
        wp   = (bf16_t*)d_ws;
        agg_clear = (size_t)NNODES * DF * sizeof(float);
    }

    bf16_t* Wp_m1 = wp;
    bf16_t* Wp_m2 = wp + 49152;
    bf16_t* Wp_u1 = wp + 65536;
    bf16_t* Wp_u2 = wp + 98304;

    prep_kernel<<<448, 256, 0, stream>>>(W_m1, W_m2, W_u1, W_u2, wp);
    (void)hipMemsetAsync(aggv, 0, agg_clear, stream);

    if (useH2) {
        msg_kernel<true><<<GST, 256, 0, stream>>>(h, e, snd, rcv,
                                                  Wp_m1, b_m1, Wp_m2, b_m2, aggv);
        upd_kernel<true><<<(NNODES + 63) / 64, 256, 0, stream>>>(h, aggv,
                                                                 Wp_u1, b_u1, Wp_u2, b_u2, out);
    } else {
        msg_kernel<false><<<GST, 256, 0, stream>>>(h, e, snd, rcv,
                                                   Wp_m1, b_m1, Wp_m2, b_m2, aggv);
        upd_kernel<false><<<(NNODES + 63) / 64, 256, 0, stream>>>(h, aggv,
                                                                  Wp_u1, b_u1, Wp_u2, b_u2, out);
    }
}

// Round 13
// 287.645 us; speedup vs baseline: 2.4475x; 2.4475x over previous
//
#include <hip/hip_runtime.h>
#include <hip/hip_bf16.h>
#include <hip/hip_fp16.h>
#include <cstdint>
#include <cstddef>

#define NNODES 50000
#define NEDGES 800000
#define DF 64
#define SROW 264    // LDS row stride in bf16 (528 B, 16B-aligned; proven r3/r6/r11)

typedef __bf16 bf16_t;
typedef __bf16 bf16x8 __attribute__((ext_vector_type(8)));
typedef __bf16 bf16x4 __attribute__((ext_vector_type(4)));
typedef __bf16 bf16x2 __attribute__((ext_vector_type(2)));
typedef float  f32x4  __attribute__((ext_vector_type(4)));
typedef _Float16 f16x2 __attribute__((ext_vector_type(2)));

// ---------------------------------------------------------------------------
// Weight packing: W[K][N] fp32 row-major -> bf16 MFMA B-fragments.
// Fragment (kblk, ct): lane l, elem j holds W[kblk*32 + (l>>4)*8 + j][ct*16 + (l&15)]
// Flat: ((kblk*(N/16) + ct)*64 + l)*8 + j.
// Segments: Wm1 @0 (49152), Wm2 @49152 (16384), Wu1 @65536 (32768), Wu2 @98304 (16384).
// ---------------------------------------------------------------------------
__global__ void prep_kernel(const float* __restrict__ Wm1, const float* __restrict__ Wm2,
                            const float* __restrict__ Wu1, const float* __restrict__ Wu2,
                            bf16_t* __restrict__ wp)
{
    int idx = blockIdx.x * 256 + threadIdx.x;
    const float* src; int N; int off; int local;
    if (idx < 49152)       { src = Wm1; N = 256; off = 0;     local = idx; }
    else if (idx < 65536)  { src = Wm2; N = 64;  off = 49152; local = idx - 49152; }
    else if (idx < 98304)  { src = Wu1; N = 256; off = 65536; local = idx - 65536; }
    else if (idx < 114688) { src = Wu2; N = 64;  off = 98304; local = idx - 98304; }
    else return;
    int j    = local & 7;
    int l    = (local >> 3) & 63;
    int frag = local >> 9;
    int nct  = N >> 4;
    int kblk = frag / nct;
    int ct   = frag - kblk * nct;
    int k = kblk * 32 + (l >> 4) * 8 + j;
    int n = ct * 16 + (l & 15);
    wp[off + local] = (bf16_t)src[(size_t)k * N + n];
}

// h (f32) -> hb (bf16), once. 3.2M elems = 800000 float4 = 3125 blocks x 256.
__global__ void hconv_kernel(const float* __restrict__ h, bf16_t* __restrict__ hb)
{
    int idx = blockIdx.x * 256 + threadIdx.x;       // < 800000 exactly
    float4 v = reinterpret_cast<const float4*>(h)[idx];
    bf16x4 bv;
    bv[0] = (bf16_t)v.x; bv[1] = (bf16_t)v.y; bv[2] = (bf16_t)v.z; bv[3] = (bf16_t)v.w;
    reinterpret_cast<bf16x4*>(hb)[idx] = bv;
}

__device__ __forceinline__ void st_bf16x4(bf16_t* p, float4 v) {
    bf16x4 bv;
    bv[0] = (bf16_t)v.x; bv[1] = (bf16_t)v.y; bv[2] = (bf16_t)v.z; bv[3] = (bf16_t)v.w;
    *reinterpret_cast<bf16x4*>(p) = bv;
}

// ---------------------------------------------------------------------------
// Message kernel: r11's proven body (128 edges/block, 512 threads, 8 waves).
// MODE 2: hb (bf16) staging for h_s/h_r + pk-f16 atomic scatter
// MODE 1: f32 h staging + pk-f16 atomic scatter
// MODE 0: f32 h staging + f32 atomics into out-aliased agg
// All modes: paired c1 writeback (shfl_xor(1) -> 32 aligned b32 DS writes,
// was 64 scalar b16 — the round-3..11 bank-conflict source).
// ---------------------------------------------------------------------------
template<int MODE>
__global__ __launch_bounds__(512, 4)
void msg_kernel(const float* __restrict__ h, const bf16_t* __restrict__ hb,
                const float* __restrict__ efeat,
                const int* __restrict__ snd, const int* __restrict__ rcv,
                const bf16_t* __restrict__ Wp1, const float* __restrict__ b1,
                const bf16_t* __restrict__ Wp2, const float* __restrict__ b2,
                void* __restrict__ aggv)
{
    __shared__ bf16_t s_buf[128 * SROW];   // 67584 B
    __shared__ int s_snd[128];
    __shared__ int s_rcv[128];

    const int t  = threadIdx.x;
    const int e0 = blockIdx.x * 128;

    if (t < 128)      s_snd[t]       = snd[e0 + t];
    else if (t < 256) s_rcv[t - 128] = rcv[e0 + t - 128];

    // e-segment (f32 -> bf16): 128 rows x 16 float4, 4 iters of 512
    #pragma unroll
    for (int it = 0; it < 4; ++it) {
        int i = t + it * 512; int row = i >> 4; int col = (i & 15) * 4;
        float4 v = *reinterpret_cast<const float4*>(efeat + (size_t)(e0 + row) * DF + col);
        st_bf16x4(&s_buf[row * SROW + col], v);
    }
    __syncthreads();   // idx visible (e-writes touch a disjoint LDS region)

    if constexpr (MODE >= 2) {
        // bf16 rows: 128 rows x 8 bf16x8 chunks = 1024 chunks, 2 iters
        #pragma unroll
        for (int it = 0; it < 2; ++it) {
            int i = t + it * 512; int row = i >> 3; int c8 = (i & 7) * 8;
            bf16x8 v = *reinterpret_cast<const bf16x8*>(hb + (size_t)s_snd[row] * DF + c8);
            *reinterpret_cast<bf16x8*>(&s_buf[row * SROW + DF + c8]) = v;
        }
        #pragma unroll
        for (int it = 0; it < 2; ++it) {
            int i = t + it * 512; int row = i >> 3; int c8 = (i & 7) * 8;
            bf16x8 v = *reinterpret_cast<const bf16x8*>(hb + (size_t)s_rcv[row] * DF + c8);
            *reinterpret_cast<bf16x8*>(&s_buf[row * SROW + 2 * DF + c8]) = v;
        }
    } else {
        #pragma unroll
        for (int it = 0; it < 4; ++it) {
            int i = t + it * 512; int row = i >> 4; int col = (i & 15) * 4;
            float4 v = *reinterpret_cast<const float4*>(h + (size_t)s_snd[row] * DF + col);
            st_bf16x4(&s_buf[row * SROW + DF + col], v);
        }
        #pragma unroll
        for (int it = 0; it < 4; ++it) {
            int i = t + it * 512; int row = i >> 4; int col = (i & 15) * 4;
            float4 v = *reinterpret_cast<const float4*>(h + (size_t)s_rcv[row] * DF + col);
            st_bf16x4(&s_buf[row * SROW + 2 * DF + col], v);
        }
    }
    __syncthreads();

    const int w = t >> 6;      // wave 0..7
    const int l = t & 63;
    const int q = l >> 4;
    const int r = l & 15;

    // ---- layer 1: M=128 (8 A-frags), N=32 per wave (ct = w*2, w*2+1) ----
    f32x4 acc[2][8];
    #pragma unroll
    for (int g = 0; g < 2; ++g)
        #pragma unroll
        for (int am = 0; am < 8; ++am) acc[g][am] = (f32x4){0.f, 0.f, 0.f, 0.f};

    #pragma unroll
    for (int kb = 0; kb < 6; ++kb) {
        bf16x8 b0 = *reinterpret_cast<const bf16x8*>(Wp1 + ((size_t)(kb * 16 + w * 2 + 0) * 64 + l) * 8);
        bf16x8 b1f = *reinterpret_cast<const bf16x8*>(Wp1 + ((size_t)(kb * 16 + w * 2 + 1) * 64 + l) * 8);
        #pragma unroll
        for (int am = 0; am < 8; ++am) {
            bf16x8 a = *reinterpret_cast<const bf16x8*>(&s_buf[(am * 16 + r) * SROW + kb * 32 + q * 8]);
            acc[0][am] = __builtin_amdgcn_mfma_f32_16x16x32_bf16(a, b0,  acc[0][am], 0, 0, 0);
            acc[1][am] = __builtin_amdgcn_mfma_f32_16x16x32_bf16(a, b1f, acc[1][am], 0, 0, 0);
        }
    }
    __syncthreads();   // all waves done reading the input tile

    // ---- paired c1 writeback: bias+relu, shfl_xor(1) col-pairing, b32 writes.
    // even lane writes rows q*4+{0,1}, odd lane rows q*4+{2,3}; each value
    // carries its own column's bias+relu (applied before the exchange).
    const bool codd = (r & 1);
    #pragma unroll
    for (int g = 0; g < 2; ++g) {
        const int colbase = (w * 2 + g) * 16;
        const float bias1 = b1[colbase + r];
        const int cp1 = colbase + (r & ~1);
        #pragma unroll
        for (int am = 0; am < 8; ++am) {
            float f0 = fmaxf(acc[g][am][0] + bias1, 0.f);
            float f1 = fmaxf(acc[g][am][1] + bias1, 0.f);
            float f2 = fmaxf(acc[g][am][2] + bias1, 0.f);
            float f3 = fmaxf(acc[g][am][3] + bias1, 0.f);
            float p0 = __shfl_xor(f0, 1), p1 = __shfl_xor(f1, 1);
            float p2 = __shfl_xor(f2, 1), p3 = __shfl_xor(f3, 1);
            float lo0 = codd ? p2 : f0, hi0 = codd ? f2 : p0;
            float lo1 = codd ? p3 : f1, hi1 = codd ? f3 : p1;
            int row0 = am * 16 + q * 4 + (codd ? 2 : 0);
            bf16x2 w0; w0[0] = (bf16_t)lo0; w0[1] = (bf16_t)hi0;
            bf16x2 w1; w1[0] = (bf16_t)lo1; w1[1] = (bf16_t)hi1;
            *reinterpret_cast<bf16x2*>(&s_buf[(size_t)row0 * SROW + cp1]) = w0;
            *reinterpret_cast<bf16x2*>(&s_buf[(size_t)(row0 + 1) * SROW + cp1]) = w1;
        }
    }
    __syncthreads();   // c1 complete

    // ---- layer 2: wave w -> rows [m2*64, m2*64+64), cols [ct2*16, ct2*16+16) ----
    const int m2  = w >> 2;
    const int ct2 = w & 3;
    f32x4 acc2[4];
    #pragma unroll
    for (int am = 0; am < 4; ++am) acc2[am] = (f32x4){0.f, 0.f, 0.f, 0.f};

    #pragma unroll
    for (int kb = 0; kb < 8; ++kb) {
        bf16x8 b = *reinterpret_cast<const bf16x8*>(Wp2 + ((size_t)(kb * 4 + ct2) * 64 + l) * 8);
        #pragma unroll
        for (int am = 0; am < 4; ++am) {
            bf16x8 a = *reinterpret_cast<const bf16x8*>(&s_buf[(m2 * 64 + am * 16 + r) * SROW + kb * 32 + q * 8]);
            acc2[am] = __builtin_amdgcn_mfma_f32_16x16x32_bf16(a, b, acc2[am], 0, 0, 0);
        }
    }

    if constexpr (MODE >= 1) {
        // packed-f16 scatter: pair adjacent cols via shfl_xor(1); even lane rows
        // q*4+{0,1}, odd lane rows q*4+{2,3}. 8 pk-atomics/thread.
        _Float16* aggh = (_Float16*)aggv;
        const int  cp  = ct2 * 16 + (r & ~1);
        const bool odd = (r & 1);
        const float blo = b2[cp], bhi = b2[cp + 1];
        #pragma unroll
        for (int am = 0; am < 4; ++am) {
            float v0 = acc2[am][0], v1 = acc2[am][1], v2 = acc2[am][2], v3 = acc2[am][3];
            float p0 = __shfl_xor(v0, 1), p1 = __shfl_xor(v1, 1);
            float p2 = __shfl_xor(v2, 1), p3 = __shfl_xor(v3, 1);
            float loA = odd ? p2 : v0, hiA = odd ? v2 : p0;
            float loB = odd ? p3 : v1, hiB = odd ? v3 : p1;
            int jbase = odd ? 2 : 0;
            int erowA = m2 * 64 + am * 16 + q * 4 + jbase;
            f16x2 hA = { (_Float16)(loA + blo), (_Float16)(hiA + bhi) };
            f16x2 hB = { (_Float16)(loB + blo), (_Float16)(hiB + bhi) };
            __builtin_amdgcn_global_atomic_fadd_v2f16(
                (f16x2*)(aggh + (size_t)s_rcv[erowA]     * DF + cp), hA);
            __builtin_amdgcn_global_atomic_fadd_v2f16(
                (f16x2*)(aggh + (size_t)s_rcv[erowA + 1] * DF + cp), hB);
        }
    } else {
        float* agg = (float*)aggv;
        const float bias2 = b2[ct2 * 16 + r];
        #pragma unroll
        for (int am = 0; am < 4; ++am)
            #pragma unroll
            for (int j = 0; j < 4; ++j) {
                int erow = m2 * 64 + am * 16 + q * 4 + j;
                atomicAdd(agg + (size_t)s_rcv[erow] * DF + ct2 * 16 + r, acc2[am][j] + bias2);
            }
    }
}

// ---------------------------------------------------------------------------
// Node-update kernel: r11's proven body + paired c1 writeback.
// MODE 2: hb (bf16) gather + f16 agg. MODE 1: f32 h + f16 agg.
// MODE 0: f32 both (agg aliases out; reads precede all stores).
// ---------------------------------------------------------------------------
template<int MODE>
__global__ __launch_bounds__(256, 4)
void upd_kernel(const float* __restrict__ h, const bf16_t* __restrict__ hb,
                const void* __restrict__ aggv,
                const bf16_t* __restrict__ Wp1, const float* __restrict__ b1,
                const bf16_t* __restrict__ Wp2, const float* __restrict__ b2,
                float* __restrict__ out)
{
    __shared__ bf16_t s_buf[64 * SROW];

    const int t  = threadIdx.x;
    const int n0 = blockIdx.x * 64;

    if constexpr (MODE >= 2) {
        // h: 64 rows x 8 bf16x8 chunks = 512 chunks, 2 iters
        #pragma unroll
        for (int it = 0; it < 2; ++it) {
            int i = t + it * 256; int nn = i >> 3; int c8 = (i & 7) * 8;
            int node = n0 + nn;
            bf16x8 v = {};
            if (node < NNODES) v = *reinterpret_cast<const bf16x8*>(hb + (size_t)node * DF + c8);
            *reinterpret_cast<bf16x8*>(&s_buf[nn * SROW + c8]) = v;
        }
    } else {
        #pragma unroll
        for (int it = 0; it < 4; ++it) {
            int i = t + it * 256; int nn = i >> 4; int col = (i & 15) * 4;
            int node = n0 + nn;
            float4 v = {0.f, 0.f, 0.f, 0.f};
            if (node < NNODES) v = *reinterpret_cast<const float4*>(h + (size_t)node * DF + col);
            st_bf16x4(&s_buf[nn * SROW + col], v);
        }
    }
    if constexpr (MODE >= 1) {
        const _Float16* aggh = (const _Float16*)aggv;
        #pragma unroll
        for (int it = 0; it < 4; ++it) {
            int i = t + it * 256; int nn = i >> 4; int col = (i & 15) * 4;
            int node = n0 + nn;
            float4 v = {0.f, 0.f, 0.f, 0.f};
            if (node < NNODES) {
                f16x2 h01 = *reinterpret_cast<const f16x2*>(aggh + (size_t)node * DF + col);
                f16x2 h23 = *reinterpret_cast<const f16x2*>(aggh + (size_t)node * DF + col + 2);
                v.x = (float)h01[0]; v.y = (float)h01[1];
                v.z = (float)h23[0]; v.w = (float)h23[1];
            }
            st_bf16x4(&s_buf[nn * SROW + DF + col], v);
        }
    } else {
        const float* agg = (const float*)aggv;
        #pragma unroll
        for (int it = 0; it < 4; ++it) {
            int i = t + it * 256; int nn = i >> 4; int col = (i & 15) * 4;
            int node = n0 + nn;
            float4 v = {0.f, 0.f, 0.f, 0.f};
            if (node < NNODES) v = *reinterpret_cast<const float4*>(agg + (size_t)node * DF + col);
            st_bf16x4(&s_buf[nn * SROW + DF + col], v);
        }
    }
    __syncthreads();

    const int w = t >> 6;
    const int l = t & 63;
    const int q = l >> 4;
    const int r = l & 15;

    f32x4 acc[4][4];
    #pragma unroll
    for (int g = 0; g < 4; ++g)
        #pragma unroll
        for (int am = 0; am < 4; ++am) acc[g][am] = (f32x4){0.f, 0.f, 0.f, 0.f};

    #pragma unroll
    for (int kb = 0; kb < 4; ++kb) {
        bf16x8 a[4];
        #pragma unroll
        for (int am = 0; am < 4; ++am)
            a[am] = *reinterpret_cast<const bf16x8*>(&s_buf[(am * 16 + r) * SROW + kb * 32 + q * 8]);
        #pragma unroll
        for (int g = 0; g < 4; ++g) {
            int ct = w * 4 + g;
            bf16x8 b = *reinterpret_cast<const bf16x8*>(Wp1 + ((size_t)(kb * 16 + ct) * 64 + l) * 8);
            #pragma unroll
            for (int am = 0; am < 4; ++am)
                acc[g][am] = __builtin_amdgcn_mfma_f32_16x16x32_bf16(a[am], b, acc[g][am], 0, 0, 0);
        }
    }
    __syncthreads();

    // paired c1 writeback (same scheme as msg)
    const bool codd = (r & 1);
    #pragma unroll
    for (int g = 0; g < 4; ++g) {
        const int colbase = (w * 4 + g) * 16;
        const float bias = b1[colbase + r];
        const int cp1 = colbase + (r & ~1);
        #pragma unroll
        for (int am = 0; am < 4; ++am) {
            float f0 = fmaxf(acc[g][am][0] + bias, 0.f);
            float f1 = fmaxf(acc[g][am][1] + bias, 0.f);
            float f2 = fmaxf(acc[g][am][2] + bias, 0.f);
            float f3 = fmaxf(acc[g][am][3] + bias, 0.f);
            float p0 = __shfl_xor(f0, 1), p1 = __shfl_xor(f1, 1);
            float p2 = __shfl_xor(f2, 1), p3 = __shfl_xor(f3, 1);
            float lo0 = codd ? p2 : f0, hi0 = codd ? f2 : p0;
            float lo1 = codd ? p3 : f1, hi1 = codd ? f3 : p1;
            int row0 = am * 16 + q * 4 + (codd ? 2 : 0);
            bf16x2 w0; w0[0] = (bf16_t)lo0; w0[1] = (bf16_t)hi0;
            bf16x2 w1; w1[0] = (bf16_t)lo1; w1[1] = (bf16_t)hi1;
            *reinterpret_cast<bf16x2*>(&s_buf[(size_t)row0 * SROW + cp1]) = w0;
            *reinterpret_cast<bf16x2*>(&s_buf[(size_t)(row0 + 1) * SROW + cp1]) = w1;
        }
    }
    __syncthreads();

    f32x4 acc2[4];
    #pragma unroll
    for (int am = 0; am < 4; ++am) acc2[am] = (f32x4){0.f, 0.f, 0.f, 0.f};

    #pragma unroll
    for (int kb = 0; kb < 8; ++kb) {
        bf16x8 a[4];
        #pragma unroll
        for (int am = 0; am < 4; ++am)
            a[am] = *reinterpret_cast<const bf16x8*>(&s_buf[(am * 16 + r) * SROW + kb * 32 + q * 8]);
        bf16x8 b = *reinterpret_cast<const bf16x8*>(Wp2 + ((size_t)(kb * 4 + w) * 64 + l) * 8);
        #pragma unroll
        for (int am = 0; am < 4; ++am)
            acc2[am] = __builtin_amdgcn_mfma_f32_16x16x32_bf16(a[am], b, acc2[am], 0, 0, 0);
    }

    // residual store: out = h + dh  (col = w*16 + r); h read in f32 for accuracy
    float bias2 = b2[w * 16 + r];
    #pragma unroll
    for (int am = 0; am < 4; ++am)
        #pragma unroll
        for (int j = 0; j < 4; ++j) {
            int node = n0 + am * 16 + q * 4 + j;
            if (node < NNODES) {
                int col = w * 16 + r;
                out[(size_t)node * DF + col] =
                    h[(size_t)node * DF + col] + acc2[am][j] + bias2;
            }
        }
}

extern "C" void kernel_launch(void* const* d_in, const int* in_sizes, int n_in,
                              void* d_out, int out_size, void* d_ws, size_t ws_size,
                              hipStream_t stream)
{
    const float* h    = (const float*)d_in[0];
    const float* e    = (const float*)d_in[1];
    const int*   snd  = (const int*)d_in[2];
    const int*   rcv  = (const int*)d_in[3];
    const float* W_m1 = (const float*)d_in[4];
    const float* b_m1 = (const float*)d_in[5];
    const float* W_m2 = (const float*)d_in[6];
    const float* b_m2 = (const float*)d_in[7];
    const float* W_u1 = (const float*)d_in[8];
    const float* b_u1 = (const float*)d_in[9];
    const float* W_u2 = (const float*)d_in[10];
    const float* b_u2 = (const float*)d_in[11];
    float* out = (float*)d_out;

    const size_t hb_bytes   = (size_t)NNODES * DF * sizeof(bf16_t);    // 6.4 MB
    const size_t aggh_bytes = (size_t)NNODES * DF * sizeof(_Float16);  // 6.4 MB
    const size_t wp_bytes   = 114688 * sizeof(bf16_t);                 // 229 KB

    int mode;
    if (ws_size >= hb_bytes + aggh_bytes + wp_bytes)      mode = 2;
    else if (ws_size >= aggh_bytes + wp_bytes)            mode = 1;
    else                                                  mode = 0;

    bf16_t* hbp = nullptr;
    void*   aggv;
    bf16_t* wp;
    size_t  agg_clear;
    if (mode == 2) {
        hbp  = (bf16_t*)d_ws;
        aggv = (char*)d_ws + hb_bytes;
        wp   = (bf16_t*)((char*)d_ws + hb_bytes + aggh_bytes);
        agg_clear = aggh_bytes;
    } else if (mode == 1) {
        aggv = d_ws;
        wp   = (bf16_t*)((char*)d_ws + aggh_bytes);
        agg_clear = aggh_bytes;
    } else {
        aggv = out;                       // alias-safe f32 path
        wp   = (bf16_t*)d_ws;
        agg_clear = (size_t)NNODES * DF * sizeof(float);
    }

    bf16_t* Wp_m1 = wp;
    bf16_t* Wp_m2 = wp + 49152;
    bf16_t* Wp_u1 = wp + 65536;
    bf16_t* Wp_u2 = wp + 98304;

    prep_kernel<<<448, 256, 0, stream>>>(W_m1, W_m2, W_u1, W_u2, wp);
    if (mode == 2) hconv_kernel<<<3125, 256, 0, stream>>>(h, hbp);
    (void)hipMemsetAsync(aggv, 0, agg_clear, stream);

    if (mode == 2) {
        msg_kernel<2><<<NEDGES / 128, 512, 0, stream>>>(h, hbp, e, snd, rcv,
                                                        Wp_m1, b_m1, Wp_m2, b_m2, aggv);
        upd_kernel<2><<<(NNODES + 63) / 64, 256, 0, stream>>>(h, hbp, aggv,
                                                              Wp_u1, b_u1, Wp_u2, b_u2, out);
    } else if (mode == 1) {
        msg_kernel<1><<<NEDGES / 128, 512, 0, stream>>>(h, nullptr, e, snd, rcv,
                                                        Wp_m1, b_m1, Wp_m2, b_m2, aggv);
        upd_kernel<1><<<(NNODES + 63) / 64, 256, 0, stream>>>(h, nullptr, aggv,
                                                              Wp_u1, b_u1, Wp_u2, b_u2, out);
    } else {
        msg_kernel<0><<<NEDGES / 128, 512, 0, stream>>>(h, nullptr, e, snd, rcv,
                                                        Wp_m1, b_m1, Wp_m2, b_m2, aggv);
        upd_kernel<0><<<(NNODES + 63) / 64, 256, 0, stream>>>(h, nullptr, aggv,
                                                              Wp_u1, b_u1, Wp_u2, b_u2, out);
    }
}

// Round 14
// 262.104 us; speedup vs baseline: 2.6860x; 1.0974x over previous
//
#include <hip/hip_runtime.h>
#include <hip/hip_bf16.h>
#include <hip/hip_fp16.h>
#include <cstdint>
#include <cstddef>

#define NNODES 50000
#define NEDGES 800000
#define DF 64
#define SROW 264    // LDS row stride in bf16 (528 B, 16B-aligned; proven r3/r6/r11)

typedef __bf16 bf16_t;
typedef __bf16 bf16x8 __attribute__((ext_vector_type(8)));
typedef __bf16 bf16x4 __attribute__((ext_vector_type(4)));
typedef float  f32x4  __attribute__((ext_vector_type(4)));
typedef _Float16 f16x2 __attribute__((ext_vector_type(2)));

// ---------------------------------------------------------------------------
// Weight packing: W[K][N] fp32 row-major -> bf16 MFMA B-fragments.
// Fragment (kblk, ct): lane l, elem j holds W[kblk*32 + (l>>4)*8 + j][ct*16 + (l&15)]
// Flat: ((kblk*(N/16) + ct)*64 + l)*8 + j.
// Segments: Wm1 @0 (49152), Wm2 @49152 (16384), Wu1 @65536 (32768), Wu2 @98304 (16384).
// ---------------------------------------------------------------------------
__global__ void prep_kernel(const float* __restrict__ Wm1, const float* __restrict__ Wm2,
                            const float* __restrict__ Wu1, const float* __restrict__ Wu2,
                            bf16_t* __restrict__ wp)
{
    int idx = blockIdx.x * 256 + threadIdx.x;
    const float* src; int N; int off; int local;
    if (idx < 49152)       { src = Wm1; N = 256; off = 0;     local = idx; }
    else if (idx < 65536)  { src = Wm2; N = 64;  off = 49152; local = idx - 49152; }
    else if (idx < 98304)  { src = Wu1; N = 256; off = 65536; local = idx - 65536; }
    else if (idx < 114688) { src = Wu2; N = 64;  off = 98304; local = idx - 98304; }
    else return;
    int j    = local & 7;
    int l    = (local >> 3) & 63;
    int frag = local >> 9;
    int nct  = N >> 4;
    int kblk = frag / nct;
    int ct   = frag - kblk * nct;
    int k = kblk * 32 + (l >> 4) * 8 + j;
    int n = ct * 16 + (l & 15);
    wp[off + local] = (bf16_t)src[(size_t)k * N + n];
}

__device__ __forceinline__ void st_bf16x4(bf16_t* p, float4 v) {
    bf16x4 bv;
    bv[0] = (bf16_t)v.x; bv[1] = (bf16_t)v.y; bv[2] = (bf16_t)v.z; bv[3] = (bf16_t)v.w;
    *reinterpret_cast<bf16x4*>(p) = bv;
}

// ---------------------------------------------------------------------------
// Message kernel: r11's proven body (128 edges/block, 512 threads, 8 waves;
// layer1 N-split 32-col/wave over all 128 edges; layer2 64 rows x 16 cols)
// + T5 s_setprio(1) around the MFMA clusters (2 independent blocks/CU at
// different phases -> scheduler role-diversity, m191 regime).
//   H2=true : packed f16 atomics (global_atomic_pk_add_f16), col-paired via
//             one __shfl_xor(1): 8 pk-atomics/thread.
//   H2=false: fp32 atomics into f32 agg aliasing out (alias-safe: upd reads
//             its agg rows before storing).
// ---------------------------------------------------------------------------
template<bool H2>
__global__ __launch_bounds__(512, 4)
void msg_kernel(const float* __restrict__ h, const float* __restrict__ efeat,
                const int* __restrict__ snd, const int* __restrict__ rcv,
                const bf16_t* __restrict__ Wp1, const float* __restrict__ b1,
                const bf16_t* __restrict__ Wp2, const float* __restrict__ b2,
                void* __restrict__ aggv)
{
    __shared__ bf16_t s_buf[128 * SROW];   // 67584 B
    __shared__ int s_snd[128];
    __shared__ int s_rcv[128];

    const int t  = threadIdx.x;
    const int e0 = blockIdx.x * 128;

    if (t < 128)      s_snd[t]       = snd[e0 + t];
    else if (t < 256) s_rcv[t - 128] = rcv[e0 + t - 128];

    // e-segment (no idx dependency): 128 rows x 16 float4, 4 iters of 512
    #pragma unroll
    for (int it = 0; it < 4; ++it) {
        int i = t + it * 512; int row = i >> 4; int col = (i & 15) * 4;
        float4 v = *reinterpret_cast<const float4*>(efeat + (size_t)(e0 + row) * DF + col);
        st_bf16x4(&s_buf[row * SROW + col], v);
    }
    __syncthreads();   // idx visible (e-writes touch a disjoint LDS region)

    #pragma unroll
    for (int it = 0; it < 4; ++it) {
        int i = t + it * 512; int row = i >> 4; int col = (i & 15) * 4;
        float4 v = *reinterpret_cast<const float4*>(h + (size_t)s_snd[row] * DF + col);
        st_bf16x4(&s_buf[row * SROW + DF + col], v);
    }
    #pragma unroll
    for (int it = 0; it < 4; ++it) {
        int i = t + it * 512; int row = i >> 4; int col = (i & 15) * 4;
        float4 v = *reinterpret_cast<const float4*>(h + (size_t)s_rcv[row] * DF + col);
        st_bf16x4(&s_buf[row * SROW + 2 * DF + col], v);
    }
    __syncthreads();

    const int w = t >> 6;      // wave 0..7
    const int l = t & 63;
    const int q = l >> 4;
    const int r = l & 15;

    // ---- layer 1: M=128 (8 A-frags), N=32 per wave (ct = w*2, w*2+1) ----
    f32x4 acc[2][8];
    #pragma unroll
    for (int g = 0; g < 2; ++g)
        #pragma unroll
        for (int am = 0; am < 8; ++am) acc[g][am] = (f32x4){0.f, 0.f, 0.f, 0.f};

    __builtin_amdgcn_s_setprio(1);
    #pragma unroll
    for (int kb = 0; kb < 6; ++kb) {
        bf16x8 b0 = *reinterpret_cast<const bf16x8*>(Wp1 + ((size_t)(kb * 16 + w * 2 + 0) * 64 + l) * 8);
        bf16x8 b1f = *reinterpret_cast<const bf16x8*>(Wp1 + ((size_t)(kb * 16 + w * 2 + 1) * 64 + l) * 8);
        #pragma unroll
        for (int am = 0; am < 8; ++am) {
            bf16x8 a = *reinterpret_cast<const bf16x8*>(&s_buf[(am * 16 + r) * SROW + kb * 32 + q * 8]);
            acc[0][am] = __builtin_amdgcn_mfma_f32_16x16x32_bf16(a, b0,  acc[0][am], 0, 0, 0);
            acc[1][am] = __builtin_amdgcn_mfma_f32_16x16x32_bf16(a, b1f, acc[1][am], 0, 0, 0);
        }
    }
    __builtin_amdgcn_s_setprio(0);
    __syncthreads();   // all waves done reading the input tile

    // bias + relu -> c1 into s_buf (row = edge, col = hidden unit)
    #pragma unroll
    for (int g = 0; g < 2; ++g) {
        const int col1 = (w * 2 + g) * 16 + r;
        const float bias1 = b1[col1];
        #pragma unroll
        for (int am = 0; am < 8; ++am)
            #pragma unroll
            for (int j = 0; j < 4; ++j)
                s_buf[(am * 16 + q * 4 + j) * SROW + col1] =
                    (bf16_t)fmaxf(acc[g][am][j] + bias1, 0.f);
    }
    __syncthreads();   // c1 complete

    // ---- layer 2: wave w -> rows [m2*64, m2*64+64), cols [ct2*16, ct2*16+16) ----
    const int m2  = w >> 2;
    const int ct2 = w & 3;
    f32x4 acc2[4];
    #pragma unroll
    for (int am = 0; am < 4; ++am) acc2[am] = (f32x4){0.f, 0.f, 0.f, 0.f};

    __builtin_amdgcn_s_setprio(1);
    #pragma unroll
    for (int kb = 0; kb < 8; ++kb) {
        bf16x8 b = *reinterpret_cast<const bf16x8*>(Wp2 + ((size_t)(kb * 4 + ct2) * 64 + l) * 8);
        #pragma unroll
        for (int am = 0; am < 4; ++am) {
            bf16x8 a = *reinterpret_cast<const bf16x8*>(&s_buf[(m2 * 64 + am * 16 + r) * SROW + kb * 32 + q * 8]);
            acc2[am] = __builtin_amdgcn_mfma_f32_16x16x32_bf16(a, b, acc2[am], 0, 0, 0);
        }
    }
    __builtin_amdgcn_s_setprio(0);

    if constexpr (H2) {
        // packed-f16 scatter: lane pair (r even/odd) covers rows q*4+{0..3} x cols {cp,cp+1}.
        // After shfl_xor(1): even lane emits rows q*4+{0,1}, odd lane rows q*4+{2,3}.
        _Float16* aggh = (_Float16*)aggv;
        const int  cp  = ct2 * 16 + (r & ~1);
        const bool odd = (r & 1);
        const float blo = b2[cp], bhi = b2[cp + 1];
        #pragma unroll
        for (int am = 0; am < 4; ++am) {
            float v0 = acc2[am][0], v1 = acc2[am][1], v2 = acc2[am][2], v3 = acc2[am][3];
            float p0 = __shfl_xor(v0, 1), p1 = __shfl_xor(v1, 1);
            float p2 = __shfl_xor(v2, 1), p3 = __shfl_xor(v3, 1);
            float loA = odd ? p2 : v0, hiA = odd ? v2 : p0;
            float loB = odd ? p3 : v1, hiB = odd ? v3 : p1;
            int jbase = odd ? 2 : 0;
            int erowA = m2 * 64 + am * 16 + q * 4 + jbase;
            f16x2 hA = { (_Float16)(loA + blo), (_Float16)(hiA + bhi) };
            f16x2 hB = { (_Float16)(loB + blo), (_Float16)(hiB + bhi) };
            __builtin_amdgcn_global_atomic_fadd_v2f16(
                (f16x2*)(aggh + (size_t)s_rcv[erowA]     * DF + cp), hA);
            __builtin_amdgcn_global_atomic_fadd_v2f16(
                (f16x2*)(aggh + (size_t)s_rcv[erowA + 1] * DF + cp), hB);
        }
    } else {
        float* agg = (float*)aggv;
        const float bias2 = b2[ct2 * 16 + r];
        #pragma unroll
        for (int am = 0; am < 4; ++am)
            #pragma unroll
            for (int j = 0; j < 4; ++j) {
                int erow = m2 * 64 + am * 16 + q * 4 + j;
                atomicAdd(agg + (size_t)s_rcv[erow] * DF + ct2 * 16 + r, acc2[am][j] + bias2);
            }
    }
}

// ---------------------------------------------------------------------------
// Node-update kernel: r11's proven body; gather reads agg as f16 (H2) or
// f32 (fallback, alias-safe when agg==out: reads precede all stores).
// ---------------------------------------------------------------------------
template<bool H2>
__global__ __launch_bounds__(256, 4)
void upd_kernel(const float* __restrict__ h, const void* __restrict__ aggv,
                const bf16_t* __restrict__ Wp1, const float* __restrict__ b1,
                const bf16_t* __restrict__ Wp2, const float* __restrict__ b2,
                float* __restrict__ out)
{
    __shared__ bf16_t s_buf[64 * SROW];

    const int t  = threadIdx.x;
    const int n0 = blockIdx.x * 64;

    if constexpr (H2) {
        const _Float16* aggh = (const _Float16*)aggv;
        #pragma unroll
        for (int it = 0; it < 4; ++it) {
            int i = t + it * 256; int nn = i >> 4; int col = (i & 15) * 4;
            int node = n0 + nn;
            float4 v = {0.f, 0.f, 0.f, 0.f};
            if (node < NNODES) v = *reinterpret_cast<const float4*>(h + (size_t)node * DF + col);
            st_bf16x4(&s_buf[nn * SROW + col], v);
        }
        #pragma unroll
        for (int it = 0; it < 4; ++it) {
            int i = t + it * 256; int nn = i >> 4; int col = (i & 15) * 4;
            int node = n0 + nn;
            float4 v = {0.f, 0.f, 0.f, 0.f};
            if (node < NNODES) {
                f16x2 h01 = *reinterpret_cast<const f16x2*>(aggh + (size_t)node * DF + col);
                f16x2 h23 = *reinterpret_cast<const f16x2*>(aggh + (size_t)node * DF + col + 2);
                v.x = (float)h01[0]; v.y = (float)h01[1];
                v.z = (float)h23[0]; v.w = (float)h23[1];
            }
            st_bf16x4(&s_buf[nn * SROW + DF + col], v);
        }
    } else {
        const float* agg = (const float*)aggv;
        #pragma unroll
        for (int it = 0; it < 8; ++it) {
            int i = t + it * 256; int nn = i >> 5; int col = (i & 31) * 4;
            int node = n0 + nn;
            float4 v = {0.f, 0.f, 0.f, 0.f};
            if (node < NNODES) {
                const float* srcp = (col < DF) ? (h + (size_t)node * DF + col)
                                               : (agg + (size_t)node * DF + (col - DF));
                v = *reinterpret_cast<const float4*>(srcp);
            }
            st_bf16x4(&s_buf[nn * SROW + col], v);
        }
    }
    __syncthreads();

    const int w = t >> 6;
    const int l = t & 63;
    const int q = l >> 4;
    const int r = l & 15;

    f32x4 acc[4][4];
    #pragma unroll
    for (int g = 0; g < 4; ++g)
        #pragma unroll
        for (int am = 0; am < 4; ++am) acc[g][am] = (f32x4){0.f, 0.f, 0.f, 0.f};

    __builtin_amdgcn_s_setprio(1);
    #pragma unroll
    for (int kb = 0; kb < 4; ++kb) {
        bf16x8 a[4];
        #pragma unroll
        for (int am = 0; am < 4; ++am)
            a[am] = *reinterpret_cast<const bf16x8*>(&s_buf[(am * 16 + r) * SROW + kb * 32 + q * 8]);
        #pragma unroll
        for (int g = 0; g < 4; ++g) {
            int ct = w * 4 + g;
            bf16x8 b = *reinterpret_cast<const bf16x8*>(Wp1 + ((size_t)(kb * 16 + ct) * 64 + l) * 8);
            #pragma unroll
            for (int am = 0; am < 4; ++am)
                acc[g][am] = __builtin_amdgcn_mfma_f32_16x16x32_bf16(a[am], b, acc[g][am], 0, 0, 0);
        }
    }
    __builtin_amdgcn_s_setprio(0);
    __syncthreads();

    #pragma unroll
    for (int g = 0; g < 4; ++g) {
        int col = (w * 4 + g) * 16 + r;
        float bias = b1[col];
        #pragma unroll
        for (int am = 0; am < 4; ++am)
            #pragma unroll
            for (int j = 0; j < 4; ++j)
                s_buf[(am * 16 + q * 4 + j) * SROW + col] =
                    (bf16_t)fmaxf(acc[g][am][j] + bias, 0.f);
    }
    __syncthreads();

    f32x4 acc2[4];
    #pragma unroll
    for (int am = 0; am < 4; ++am) acc2[am] = (f32x4){0.f, 0.f, 0.f, 0.f};

    __builtin_amdgcn_s_setprio(1);
    #pragma unroll
    for (int kb = 0; kb < 8; ++kb) {
        bf16x8 a[4];
        #pragma unroll
        for (int am = 0; am < 4; ++am)
            a[am] = *reinterpret_cast<const bf16x8*>(&s_buf[(am * 16 + r) * SROW + kb * 32 + q * 8]);
        bf16x8 b = *reinterpret_cast<const bf16x8*>(Wp2 + ((size_t)(kb * 4 + w) * 64 + l) * 8);
        #pragma unroll
        for (int am = 0; am < 4; ++am)
            acc2[am] = __builtin_amdgcn_mfma_f32_16x16x32_bf16(a[am], b, acc2[am], 0, 0, 0);
    }
    __builtin_amdgcn_s_setprio(0);

    float bias2 = b2[w * 16 + r];
    #pragma unroll
    for (int am = 0; am < 4; ++am)
        #pragma unroll
        for (int j = 0; j < 4; ++j) {
            int node = n0 + am * 16 + q * 4 + j;
            if (node < NNODES) {
                int col = w * 16 + r;
                out[(size_t)node * DF + col] =
                    h[(size_t)node * DF + col] + acc2[am][j] + bias2;
            }
        }
}

extern "C" void kernel_launch(void* const* d_in, const int* in_sizes, int n_in,
                              void* d_out, int out_size, void* d_ws, size_t ws_size,
                              hipStream_t stream)
{
    const float* h    = (const float*)d_in[0];
    const float* e    = (const float*)d_in[1];
    const int*   snd  = (const int*)d_in[2];
    const int*   rcv  = (const int*)d_in[3];
    const float* W_m1 = (const float*)d_in[4];
    const float* b_m1 = (const float*)d_in[5];
    const float* W_m2 = (const float*)d_in[6];
    const float* b_m2 = (const float*)d_in[7];
    const float* W_u1 = (const float*)d_in[8];
    const float* b_u1 = (const float*)d_in[9];
    const float* W_u2 = (const float*)d_in[10];
    const float* b_u2 = (const float*)d_in[11];
    float* out = (float*)d_out;

    const size_t aggh_bytes = (size_t)NNODES * DF * sizeof(_Float16);  // 6.4 MB
    const size_t wp_bytes   = 114688 * sizeof(bf16_t);                 // 229 KB

    const bool useH2 = (ws_size >= aggh_bytes + wp_bytes);

    void*   aggv;
    bf16_t* wp;
    size_t  agg_clear;
    if (useH2) {
        aggv = d_ws;
        wp   = (bf16_t*)((char*)d_ws + aggh_bytes);
        agg_clear = aggh_bytes;
    } else {
        aggv = out;                       // legacy alias-safe f32 path
        wp   = (bf16_t*)d_ws;
        agg_clear = (size_t)NNODES * DF * sizeof(float);
    }

    bf16_t* Wp_m1 = wp;
    bf16_t* Wp_m2 = wp + 49152;
    bf16_t* Wp_u1 = wp + 65536;
    bf16_t* Wp_u2 = wp + 98304;

    prep_kernel<<<448, 256, 0, stream>>>(W_m1, W_m2, W_u1, W_u2, wp);
    (void)hipMemsetAsync(aggv, 0, agg_clear, stream);

    if (useH2) {
        msg_kernel<true><<<NEDGES / 128, 512, 0, stream>>>(h, e, snd, rcv,
                                                           Wp_m1, b_m1, Wp_m2, b_m2, aggv);
        upd_kernel<true><<<(NNODES + 63) / 64, 256, 0, stream>>>(h, aggv,
                                                                 Wp_u1, b_u1, Wp_u2, b_u2, out);
    } else {
        msg_kernel<false><<<NEDGES / 128, 512, 0, stream>>>(h, e, snd, rcv,
                                                            Wp_m1, b_m1, Wp_m2, b_m2, aggv);
        upd_kernel<false><<<(NNODES + 63) / 64, 256, 0, stream>>>(h, aggv,
                                                                  Wp_u1, b_u1, Wp_u2, b_u2, out);
    }
}